// Round 12
// baseline (592.672 us; speedup 1.0000x reference)
//
#include <hip/hip_runtime.h>
#include <hip/hip_cooperative_groups.h>
#include <math.h>

namespace cg = cooperative_groups;

#define NND 6144
#define NED 12288
#define GRID 1024
static constexpr float EPS_BN = 1e-5f;

// ---------------- ws layout (float offsets) ----------------
#define HN_OFF    0         // Hn [N,32]
#define HE_OFF    196608    // he [N,2]
#define ST_OFF    208896    // [64]: sum0[16] sq0[16] | us5[5]
#define Y_OFF     208960    // YT [32,N]
#define T0_OFF    405568    // H [N,32] / Zc0 [E,16]
#define T1_OFF    602176    // ZtT [16,E]
#define Z0_OFF    798784    // [E]
#define Z1_OFF    811072    // [E]
#define U_OFF     823360    // [E]
#define S_OFF     835648    // [E]
#define PP_OFF    847936    // head partials [128][N]

typedef float floatx4 __attribute__((ext_vector_type(4)));

__device__ __forceinline__ float4 ntload4(const float* p) {
  floatx4 v = __builtin_nontemporal_load(reinterpret_cast<const floatx4*>(p));
  return make_float4(v.x, v.y, v.z, v.w);
}
__device__ __forceinline__ float4 ld4(const float* p) {
  return *reinterpret_cast<const float4*>(p);
}
__device__ __forceinline__ void gll16(const float* g, float* l) {
  __builtin_amdgcn_global_load_lds(
      (const __attribute__((address_space(1))) unsigned int*)g,
      (__attribute__((address_space(3))) unsigned int*)l, 16, 0, 0);
}

struct Params {
  const float *X_n, *X_e, *A, *L1, *B1;
  const float *gW0, *gb0, *gW1, *gb1;
  const float *tW0, *tb0, *bng0, *bnb0;
  const float *tW1, *tb1, *bng1, *bnb1;
  const float *fc1W, *fc1b, *fc2W, *fc2b;
  float *ws;
  float *out;
};

// PHASE == 0: full pipeline with grid.sync (cooperative launch).
// PHASE == k (1..11): only phase k (fallback, one kernel per phase).
// waves_per_eu(4,4): pin exactly 4 waves/EU (4 blocks/CU) -> VGPR cap 128,
// and no compiler incentive to squeeze to 64 (which spilled head's h[3][34]).
template<int PHASE>
__global__ __launch_bounds__(256)
__attribute__((amdgpu_waves_per_eu(4, 4)))
void pipeline(Params p) {
  __shared__ float lds[10240];              // 40 KB pool -> 4 blocks/CU
  float* sst = &lds[10176];                 // 32-float scratch
  float* red = &lds[10208];                 // 20-float scratch

  const int tid  = threadIdx.x;
  const int lane = tid & 63;
  const int w    = tid >> 6;
  const int blk  = blockIdx.x;
  const int gtid = blk * 256 + tid;
  constexpr bool ALL = (PHASE == 0);

  float* Hn = p.ws + HN_OFF;
  float* he = p.ws + HE_OFF;
  float* st = p.ws + ST_OFF;
  float* Y  = p.ws + Y_OFF;
  float* T0 = p.ws + T0_OFF;
  float* T1 = p.ws + T1_OFF;
  float* Z0 = p.ws + Z0_OFF;
  float* Z1 = p.ws + Z1_OFF;
  float* u  = p.ws + U_OFF;
  float* s  = p.ws + S_OFF;
  float* pp = p.ws + PP_OFF;

  // gemm32: out = relu(A@Y^T + b). 6 rows/block; wave = 3 rows x 16 cols.
  // LDS: Y 32x256 (lds[0..8191]) + A 6x256 (lds[8192..9727]).
  auto gemm32 = [&](const float* bias, float* outp) {
    const int rg = w >> 1, cg_ = w & 1;
    const int r0 = blk * 6;
    const int c0 = cg_ * 16;
    float acc[3][16];
    #pragma unroll
    for (int r = 0; r < 3; ++r)
      #pragma unroll
      for (int c = 0; c < 16; ++c) acc[r][c] = 0.f;

    for (int kb = 0; kb < NND; kb += 256) {
      #pragma unroll
      for (int i = 0; i < 8; ++i) {
        const int yr = w * 8 + i;
        gll16(Y + (size_t)yr * NND + kb + lane * 4, &lds[yr * 256]);
      }
      #pragma unroll
      for (int i = 0; i < 2; ++i) {
        const int ar = w * 2 + i;
        if (ar < 6)
          gll16(p.A + (size_t)(r0 + ar) * NND + kb + lane * 4, &lds[8192 + ar * 256]);
      }
      __syncthreads();
      float4 av[3];
      #pragma unroll
      for (int r = 0; r < 3; ++r)
        av[r] = ld4(&lds[8192 + (rg * 3 + r) * 256 + lane * 4]);
      #pragma unroll
      for (int c = 0; c < 16; ++c) {
        const float4 y = ld4(&lds[(c0 + c) * 256 + lane * 4]);
        #pragma unroll
        for (int r = 0; r < 3; ++r) {
          acc[r][c] = fmaf(av[r].x, y.x, acc[r][c]);
          acc[r][c] = fmaf(av[r].y, y.y, acc[r][c]);
          acc[r][c] = fmaf(av[r].z, y.z, acc[r][c]);
          acc[r][c] = fmaf(av[r].w, y.w, acc[r][c]);
        }
      }
      __syncthreads();
    }
    // per-row: fold bits 5,4 then compact 16 values over bits 3..0
    #pragma unroll
    for (int r = 0; r < 3; ++r) {
      float wv[16];
      #pragma unroll
      for (int c = 0; c < 16; ++c) {
        float t = acc[r][c] + __shfl_xor(acc[r][c], 32, 64);
        wv[c] = t + __shfl_xor(t, 16, 64);
      }
      #pragma unroll
      for (int b = 3; b >= 0; --b) {
        const int m = 1 << b;
        const bool hi = (lane & m) != 0;
        #pragma unroll
        for (int i = 0; i < (1 << b); ++i) {
          float x = wv[i], yv = wv[i + (1 << b)];
          float send = hi ? x : yv;
          float recv = __shfl_xor(send, m, 64);
          wv[i] = (hi ? yv : x) + recv;
        }
      }
      if (lane < 16) {
        float v = fmaxf(wv[0] + bias[c0 + lane], 0.f);
        outp[(size_t)(r0 + rg * 3 + r) * 32 + c0 + lane] = v;
      }
    }
  };

  // ---- P1: zero stats; Y0T = X_n@gW0^T; ZtT = X_e@tW0^T + tb0 ----
  if constexpr (ALL || PHASE == 1) {
    if (blk == 0 && tid < 64) st[tid] = 0.f;
    if (gtid < NND) {
      const int m = gtid;
      float x[32];
      #pragma unroll
      for (int k = 0; k < 32; k += 4) {
        float4 v = ld4(p.X_n + (size_t)m * 32 + k);
        x[k] = v.x; x[k+1] = v.y; x[k+2] = v.z; x[k+3] = v.w;
      }
      #pragma unroll
      for (int oc = 0; oc < 32; ++oc) {
        float acc = 0.f;
        #pragma unroll
        for (int k = 0; k < 32; ++k) acc = fmaf(x[k], p.gW0[oc * 32 + k], acc);
        Y[(size_t)oc * NND + m] = acc;
      }
    } else if (gtid < NND + NED) {
      const int e = gtid - NND;
      float x[16];
      #pragma unroll
      for (int k = 0; k < 16; k += 4) {
        float4 v = ld4(p.X_e + (size_t)e * 16 + k);
        x[k] = v.x; x[k+1] = v.y; x[k+2] = v.z; x[k+3] = v.w;
      }
      #pragma unroll
      for (int oc = 0; oc < 16; ++oc) {
        float acc = p.tb0[oc];
        #pragma unroll
        for (int k = 0; k < 16; ++k) acc = fmaf(x[k], p.tW0[oc * 16 + k], acc);
        T1[(size_t)oc * NED + e] = acc;
      }
    }
  }
  if constexpr (ALL) cg::this_grid().sync();

  // ---- P2: H(T0) = relu(A@Y0 + gb0) ----
  if constexpr (ALL || PHASE == 2) gemm32(p.gb0, T0);
  if constexpr (ALL) cg::this_grid().sync();

  // ---- P3: Y1T = H@gW1^T ----
  if constexpr (ALL || PHASE == 3) {
    if (gtid < NND) {
      const int m = gtid;
      float x[32];
      #pragma unroll
      for (int k = 0; k < 32; k += 4) {
        float4 v = ld4(T0 + (size_t)m * 32 + k);
        x[k] = v.x; x[k+1] = v.y; x[k+2] = v.z; x[k+3] = v.w;
      }
      #pragma unroll
      for (int oc = 0; oc < 32; ++oc) {
        float acc = 0.f;
        #pragma unroll
        for (int k = 0; k < 32; ++k) acc = fmaf(x[k], p.gW1[oc * 32 + k], acc);
        Y[(size_t)oc * NND + m] = acc;
      }
    }
  }
  if constexpr (ALL) cg::this_grid().sync();

  // ---- P4: Hn = relu(A@Y1 + gb1) ----
  if constexpr (ALL || PHASE == 4) gemm32(p.gb1, Hn);
  if constexpr (ALL) cg::this_grid().sync();

  // ---- P5: Zc0(T0) = L1@ZtT^T + fused BN stats -- PIPELINED ----
  // 12 rows/block; wave = 3 rows x 16 cols. L1 rows in REGISTERS (depth-1),
  // Zt panel DOUBLE-BUFFERED in LDS (2 x 16 rows x 256 = 2 x 16 KB).
  // Counted vmcnt(7): next chunk's 7 loads stay in flight across compute.
  if constexpr (ALL || PHASE == 5) {
    const int r0 = blk * 12;
    const float* mp[3];
    #pragma unroll
    for (int r = 0; r < 3; ++r) mp[r] = p.L1 + (size_t)(r0 + w * 3 + r) * NED;

    float acc[3][16];
    #pragma unroll
    for (int r = 0; r < 3; ++r)
      #pragma unroll
      for (int c = 0; c < 16; ++c) acc[r][c] = 0.f;

    auto stageZt = [&](int kb, int b) {
      #pragma unroll
      for (int i = 0; i < 4; ++i) {
        const int yr = w * 4 + i;
        gll16(T1 + (size_t)yr * NED + kb + lane * 4, &lds[b * 4096 + yr * 256]);
      }
    };
    float4 aC[3], aN[3];
    auto issueA = [&](int kb, float4* d) {
      #pragma unroll
      for (int r = 0; r < 3; ++r) d[r] = ld4(mp[r] + kb + lane * 4);
    };

    // prologue: chunk 0 staged + drained once
    issueA(0, aC);
    stageZt(0, 0);
    asm volatile("s_waitcnt vmcnt(0)" ::: "memory");
    __builtin_amdgcn_sched_barrier(0);
    __builtin_amdgcn_s_barrier();

    constexpr int NCH = NED / 256;   // 48
    for (int i = 0; i < NCH; ++i) {
      const int pb = i & 1;
      const bool more = (i + 1) < NCH;
      if (more) {
        issueA((i + 1) * 256, aN);
        stageZt((i + 1) * 256, pb ^ 1);   // safe: end-of-iter barrier of i-1
        asm volatile("s_waitcnt vmcnt(7)" ::: "memory");  // drain chunk i only
      } else {
        asm volatile("s_waitcnt vmcnt(0)" ::: "memory");
      }
      __builtin_amdgcn_sched_barrier(0);
      __builtin_amdgcn_s_barrier();     // chunk i visible to all waves
      __builtin_amdgcn_sched_barrier(0);
      #pragma unroll
      for (int c = 0; c < 16; ++c) {
        const float4 y = ld4(&lds[pb * 4096 + c * 256 + lane * 4]);
        #pragma unroll
        for (int r = 0; r < 3; ++r) {
          acc[r][c] = fmaf(aC[r].x, y.x, acc[r][c]);
          acc[r][c] = fmaf(aC[r].y, y.y, acc[r][c]);
          acc[r][c] = fmaf(aC[r].z, y.z, acc[r][c]);
          acc[r][c] = fmaf(aC[r].w, y.w, acc[r][c]);
        }
      }
      if (more) { aC[0] = aN[0]; aC[1] = aN[1]; aC[2] = aN[2]; }
      __builtin_amdgcn_s_barrier();     // all done reading buf[pb]
    }

    float stS = 0.f, stQ = 0.f;
    #pragma unroll
    for (int r = 0; r < 3; ++r) {
      float wv[16];
      #pragma unroll
      for (int c = 0; c < 16; ++c) {
        float t = acc[r][c] + __shfl_xor(acc[r][c], 32, 64);
        wv[c] = t + __shfl_xor(t, 16, 64);
      }
      #pragma unroll
      for (int b = 3; b >= 0; --b) {
        const int m = 1 << b;
        const bool hi = (lane & m) != 0;
        #pragma unroll
        for (int i = 0; i < (1 << b); ++i) {
          float x = wv[i], yv = wv[i + (1 << b)];
          float send = hi ? x : yv;
          float recv = __shfl_xor(send, m, 64);
          wv[i] = (hi ? yv : x) + recv;
        }
      }
      if (lane < 16) {
        const float v = wv[0];
        T0[(size_t)(r0 + w * 3 + r) * 16 + lane] = v;
        stS += v; stQ += v * v;
      }
    }
    if (tid < 32) sst[tid] = 0.f;
    __syncthreads();
    if (lane < 16) {
      atomicAdd(&sst[lane], stS);
      atomicAdd(&sst[16 + lane], stQ);
    }
    __syncthreads();
    if (tid < 32) atomicAdd(st + tid, sst[tid]);
  }
  if constexpr (ALL) cg::this_grid().sync();

  // ---- P6: Z0 = relu(max_c BN(Zc0)) ----
  if constexpr (ALL || PHASE == 6) {
    if (gtid < NED) {
      const int e = gtid;
      const float invE = 1.f / (float)NED;
      float best = -3.4e38f;
      #pragma unroll
      for (int c = 0; c < 16; ++c) {
        float m = st[c] * invE;
        float var = st[16 + c] * invE - m * m;
        float sc = p.bng0[c] * rsqrtf(var + EPS_BN);
        float sh = p.bnb0[c] - m * sc;
        best = fmaxf(best, fmaf(T0[(size_t)e * 16 + c], sc, sh));
      }
      Z0[e] = fmaxf(best, 0.f);
    }
  }
  if constexpr (ALL) cg::this_grid().sync();

  // ---- P7: u = L1@Z0, s = L1@1, fused st5. REV order (L3 tail reuse). ----
  if constexpr (ALL || PHASE == 7) {
    const int rb = GRID - 1 - blk;
    const int r0 = rb * 12 + w * 3;
    const float* mp[3];
    #pragma unroll
    for (int r = 0; r < 3; ++r) mp[r] = p.L1 + (size_t)(r0 + r) * NED;
    float ua[3] = {0,0,0}, sa[3] = {0,0,0};
    float4 a[3], an[3];
    #pragma unroll
    for (int r = 0; r < 3; ++r) a[r] = ntload4(mp[r] + lane * 4);
    float4 z = ld4(Z0 + lane * 4), zn;
    for (int kb = 0; kb < NED; kb += 256) {
      const int k = kb + lane * 4;
      const bool more = (kb + 256) < NED;
      if (more) {
        #pragma unroll
        for (int r = 0; r < 3; ++r) an[r] = ntload4(mp[r] + k + 256);
        zn = ld4(Z0 + k + 256);
      }
      #pragma unroll
      for (int r = 0; r < 3; ++r) {
        ua[r] += a[r].x*z.x + a[r].y*z.y + a[r].z*z.z + a[r].w*z.w;
        sa[r] += a[r].x + a[r].y + a[r].z + a[r].w;
      }
      if (more) {
        #pragma unroll
        for (int r = 0; r < 3; ++r) a[r] = an[r];
        z = zn;
      }
    }
    #pragma unroll
    for (int r = 0; r < 3; ++r)
      #pragma unroll
      for (int m = 1; m < 64; m <<= 1) {
        ua[r] += __shfl_xor(ua[r], m, 64);
        sa[r] += __shfl_xor(sa[r], m, 64);
      }
    if (lane == 0) {
      float s1 = 0.f, s2 = 0.f, s3 = 0.f, s4 = 0.f, s5 = 0.f;
      #pragma unroll
      for (int r = 0; r < 3; ++r) {
        u[r0 + r] = ua[r]; s[r0 + r] = sa[r];
        s1 += ua[r]; s2 += sa[r];
        s3 += ua[r] * ua[r]; s4 += sa[r] * sa[r]; s5 += ua[r] * sa[r];
      }
      red[w * 5 + 0] = s1; red[w * 5 + 1] = s2; red[w * 5 + 2] = s3;
      red[w * 5 + 3] = s4; red[w * 5 + 4] = s5;
    }
    __syncthreads();
    if (tid < 5)
      atomicAdd(st + 32 + tid, red[tid] + red[5 + tid] + red[10 + tid] + red[15 + tid]);
  }
  if constexpr (ALL) cg::this_grid().sync();

  // ---- P8: Z1 from (u,s) via collapsed BN ----
  if constexpr (ALL || PHASE == 8) {
    if (gtid < NED) {
      const int e = gtid;
      const float invE = 1.f / (float)NED;
      const float Su = st[32], Ss = st[33], Suu = st[34], Sss = st[35], Sus = st[36];
      const float uu = u[e], ssv = s[e];
      float best = -3.4e38f;
      #pragma unroll
      for (int c = 0; c < 16; ++c) {
        const float wc = p.tW1[c], bc = p.tb1[c];
        const float mean = (wc * Su + bc * Ss) * invE;
        const float ex2 = (wc * wc * Suu + 2.f * wc * bc * Sus + bc * bc * Sss) * invE;
        const float var = ex2 - mean * mean;
        const float sc = p.bng1[c] * rsqrtf(var + EPS_BN);
        const float sh = p.bnb1[c] - mean * sc;
        best = fmaxf(best, fmaf(wc * uu + bc * ssv, sc, sh));
      }
      Z1[e] = fmaxf(best, 0.f);
    }
  }
  if constexpr (ALL) cg::this_grid().sync();

  // ---- P9: he = B1 @ [Z0 Z1]. 12 rows/block, 3 rows/wave. ----
  if constexpr (ALL || PHASE == 9) {
    const int r0 = blk * 12 + w * 3;
    if (r0 < NND) {
      const float* mp[3];
      #pragma unroll
      for (int r = 0; r < 3; ++r) mp[r] = p.B1 + (size_t)(r0 + r) * NED;
      float uu[3] = {0,0,0}, vv[3] = {0,0,0};
      float4 a[3], an[3];
      #pragma unroll
      for (int r = 0; r < 3; ++r) a[r] = ntload4(mp[r] + lane * 4);
      float4 z = ld4(Z0 + lane * 4), y = ld4(Z1 + lane * 4), zn, yn;
      for (int kb = 0; kb < NED; kb += 256) {
        const int k = kb + lane * 4;
        const bool more = (kb + 256) < NED;
        if (more) {
          #pragma unroll
          for (int r = 0; r < 3; ++r) an[r] = ntload4(mp[r] + k + 256);
          zn = ld4(Z0 + k + 256); yn = ld4(Z1 + k + 256);
        }
        #pragma unroll
        for (int r = 0; r < 3; ++r) {
          uu[r] += a[r].x*z.x + a[r].y*z.y + a[r].z*z.z + a[r].w*z.w;
          vv[r] += a[r].x*y.x + a[r].y*y.y + a[r].z*y.z + a[r].w*y.w;
        }
        if (more) {
          #pragma unroll
          for (int r = 0; r < 3; ++r) a[r] = an[r];
          z = zn; y = yn;
        }
      }
      #pragma unroll
      for (int r = 0; r < 3; ++r)
        #pragma unroll
        for (int m = 1; m < 64; m <<= 1) {
          uu[r] += __shfl_xor(uu[r], m, 64);
          vv[r] += __shfl_xor(vv[r], m, 64);
        }
      if (lane == 0) {
        #pragma unroll
        for (int r = 0; r < 3; ++r) {
          he[(r0 + r) * 2]     = uu[r];
          he[(r0 + r) * 2 + 1] = vv[r];
        }
      }
    }
  }
  if constexpr (ALL) cg::this_grid().sync();

  // ---- P10: head partials. blk -> (nb=blk&7, jb=blk>>3); 128 chunks x 96 j. ----
  if constexpr (ALL || PHASE == 10) {
    const int nb = blk & 7, jb = blk >> 3;
    int n[3];
    float h[3][34];
    float acc[3] = {0.f, 0.f, 0.f};
    #pragma unroll
    for (int i = 0; i < 3; ++i) {
      n[i] = nb * 768 + i * 256 + tid;
      #pragma unroll
      for (int k = 0; k < 32; k += 4) {
        float4 v = ld4(Hn + (size_t)n[i] * 32 + k);
        h[i][k] = v.x; h[i][k+1] = v.y; h[i][k+2] = v.z; h[i][k+3] = v.w;
      }
      float2 e2 = *reinterpret_cast<const float2*>(he + n[i] * 2);
      h[i][32] = e2.x; h[i][33] = e2.y;
    }
    const int j0 = jb * 96;
    for (int j = j0; j < j0 + 96; ++j) {
      const float* wp = p.fc1W + (size_t)j * 34;
      const float bj = p.fc1b[j], vj = p.fc2W[j];
      float s0 = bj, s1 = bj, s2 = bj;
      #pragma unroll
      for (int k = 0; k < 34; ++k) {
        const float wk = wp[k];
        s0 = fmaf(h[0][k], wk, s0);
        s1 = fmaf(h[1][k], wk, s1);
        s2 = fmaf(h[2][k], wk, s2);
      }
      acc[0] += fmaxf(s0, 0.f) * vj;
      acc[1] += fmaxf(s1, 0.f) * vj;
      acc[2] += fmaxf(s2, 0.f) * vj;
    }
    #pragma unroll
    for (int i = 0; i < 3; ++i) pp[(size_t)jb * NND + n[i]] = acc[i];
  }
  if constexpr (ALL) cg::this_grid().sync();

  // ---- P11: final reduce + sigmoid ----
  if constexpr (ALL || PHASE == 11) {
    if (gtid < NND) {
      float acc = 0.f;
      for (int j = 0; j < 128; ++j) acc += pp[(size_t)j * NND + gtid];
      p.out[gtid] = 1.f / (1.f + expf(-(acc + p.fc2b[0])));
    }
  }
}

extern "C" void kernel_launch(void* const* d_in, const int* in_sizes, int n_in,
                              void* d_out, int out_size, void* d_ws, size_t ws_size,
                              hipStream_t stream) {
  Params p;
  p.X_n  = (const float*)d_in[0];
  p.X_e  = (const float*)d_in[1];
  p.A    = (const float*)d_in[2];
  p.L1   = (const float*)d_in[3];
  p.B1   = (const float*)d_in[4];
  p.gW0  = (const float*)d_in[5];
  p.gb0  = (const float*)d_in[6];
  p.gW1  = (const float*)d_in[7];
  p.gb1  = (const float*)d_in[8];
  p.tW0  = (const float*)d_in[9];
  p.tb0  = (const float*)d_in[10];
  p.bng0 = (const float*)d_in[11];
  p.bnb0 = (const float*)d_in[12];
  p.tW1  = (const float*)d_in[13];
  p.tb1  = (const float*)d_in[14];
  p.bng1 = (const float*)d_in[15];
  p.bnb1 = (const float*)d_in[16];
  p.fc1W = (const float*)d_in[17];
  p.fc1b = (const float*)d_in[18];
  p.fc2W = (const float*)d_in[19];
  p.fc2b = (const float*)d_in[20];
  p.ws   = (float*)d_ws;
  p.out  = (float*)d_out;

  // Cooperative only if 1024 blocks are guaranteed co-resident (4/CU x 256 CU).
  int maxBlk = 0;
  hipError_t oe = hipOccupancyMaxActiveBlocksPerMultiprocessor(
      &maxBlk, pipeline<0>, 256, 0);
  bool coop_ok = (oe == hipSuccess) && (maxBlk >= 4);

  if (coop_ok) {
    void* kargs[] = { &p };
    hipError_t le = hipLaunchCooperativeKernel(
        (const void*)&pipeline<0>, dim3(GRID), dim3(256), kargs, 0, stream);
    if (le == hipSuccess) return;
  }

  // Fallback: identical phases as separate kernels.
  pipeline<1><<<GRID, 256, 0, stream>>>(p);
  pipeline<2><<<GRID, 256, 0, stream>>>(p);
  pipeline<3><<<GRID, 256, 0, stream>>>(p);
  pipeline<4><<<GRID, 256, 0, stream>>>(p);
  pipeline<5><<<GRID, 256, 0, stream>>>(p);
  pipeline<6><<<GRID, 256, 0, stream>>>(p);
  pipeline<7><<<GRID, 256, 0, stream>>>(p);
  pipeline<8><<<GRID, 256, 0, stream>>>(p);
  pipeline<9><<<GRID, 256, 0, stream>>>(p);
  pipeline<10><<<GRID, 256, 0, stream>>>(p);
  pipeline<11><<<GRID, 256, 0, stream>>>(p);
}